// Round 1
// baseline (1072.651 us; speedup 1.0000x reference)
//
#include <hip/hip_runtime.h>
#include <hip/hip_bf16.h>

#define S_  2048
#define B_  2
#define H_  1024
#define NH_ 16
#define D_  64
#define N3_ 3072   // 3*H
#define SB_ 4096   // S*B

typedef short s16x8 __attribute__((ext_vector_type(8)));
typedef float f32x4 __attribute__((ext_vector_type(4)));
typedef unsigned short u16;

__device__ __forceinline__ u16 f2bf(float f) {
    __hip_bfloat16 h = __float2bfloat16(f);
    union { __hip_bfloat16 h; u16 u; } c; c.h = h; return c.u;
}

// ---------------------------------------------------------------------------
// Kernel 1: fused QKV projection.  qkv[m][n] = sum_k hidden[m][k]*W[n][k] + b[n]
// m = s*B + b (row-major [S,B,H]); n = h*192 + c*64 + d  (c: 0=q 1=k 2=v)
// Writes bf16:  Q[bh][s][d], K[bh][s][d], Vt[bh][d][s]   (bh = b*16+h)
// 128x128 tile, BK=64, 4 waves (2x2), 16x16x32 bf16 MFMA, XOR-swizzled LDS.
// ---------------------------------------------------------------------------
__global__ __launch_bounds__(256) void qkv_gemm(
    const float* __restrict__ A, const float* __restrict__ W,
    const float* __restrict__ bias,
    u16* __restrict__ Qb, u16* __restrict__ Kb, u16* __restrict__ Vt)
{
    __shared__ u16 As[128 * 64];
    __shared__ u16 Bs[128 * 64];

    const int tid  = threadIdx.x;
    const int lane = tid & 63;
    const int w    = tid >> 6;
    const int wm   = (w >> 1) * 64;
    const int wn   = (w & 1) * 64;
    const int l15  = lane & 15;
    const int lg   = lane >> 4;
    const int mBase = blockIdx.y * 128;
    const int nBase = blockIdx.x * 128;

    f32x4 acc[4][4] = {};

    for (int kt = 0; kt < 1024; kt += 64) {
        __syncthreads();
        // stage A (hidden) and B (W) tiles: fp32 -> bf16, swizzled LDS
        #pragma unroll
        for (int i = 0; i < 8; ++i) {
            int chunk = tid + i * 256;           // 0..2047
            int row = chunk >> 4, c4 = chunk & 15;
            float4 av = *(const float4*)(A + (size_t)(mBase + row) * 1024 + kt + c4 * 4);
            float4 bv = *(const float4*)(W + (size_t)(nBase + row) * 1024 + kt + c4 * 4);
            int byte = (row * 128 + c4 * 8) ^ ((row & 7) << 4);
            ushort4 ap; ap.x = f2bf(av.x); ap.y = f2bf(av.y); ap.z = f2bf(av.z); ap.w = f2bf(av.w);
            ushort4 bp; bp.x = f2bf(bv.x); bp.y = f2bf(bv.y); bp.z = f2bf(bv.z); bp.w = f2bf(bv.w);
            *(ushort4*)((char*)As + byte) = ap;
            *(ushort4*)((char*)Bs + byte) = bp;
        }
        __syncthreads();

        #pragma unroll
        for (int kk = 0; kk < 2; ++kk) {
            s16x8 af[4], bfr[4];
            #pragma unroll
            for (int mi = 0; mi < 4; ++mi) {
                int row = wm + mi * 16 + l15;
                int byte = (row * 128 + ((kk * 64 + lg * 16) ^ ((row & 7) << 4)));
                af[mi] = *(const s16x8*)((const char*)As + byte);
            }
            #pragma unroll
            for (int ni = 0; ni < 4; ++ni) {
                int row = wn + ni * 16 + l15;
                int byte = (row * 128 + ((kk * 64 + lg * 16) ^ ((row & 7) << 4)));
                bfr[ni] = *(const s16x8*)((const char*)Bs + byte);
            }
            #pragma unroll
            for (int mi = 0; mi < 4; ++mi)
                #pragma unroll
                for (int ni = 0; ni < 4; ++ni)
                    acc[mi][ni] = __builtin_amdgcn_mfma_f32_16x16x32_bf16(
                        af[mi], bfr[ni], acc[mi][ni], 0, 0, 0);
        }
    }

    // epilogue: bias add, scatter to Q / K / Vt (bf16)
    #pragma unroll
    for (int ni = 0; ni < 4; ++ni) {
        int gn = nBase + wn + ni * 16 + l15;   // global n, wave-uniform c/h per ni
        float bv = bias[gn];
        int h  = gn / 192;
        int r  = gn - h * 192;
        int c  = r >> 6;
        int dd = r & 63;
        #pragma unroll
        for (int mi = 0; mi < 4; ++mi) {
            #pragma unroll
            for (int j = 0; j < 4; ++j) {
                int m = mBase + wm + mi * 16 + lg * 4 + j;   // C/D: row=(lg)*4+j
                float val = acc[mi][ni][j] + bv;
                int s = m >> 1, b = m & 1;
                int bh = b * 16 + h;
                u16 o = f2bf(val);
                if (c == 0)      Qb[((size_t)bh * S_ + s) * 64 + dd] = o;
                else if (c == 1) Kb[((size_t)bh * S_ + s) * 64 + dd] = o;
                else             Vt[((size_t)bh * 64 + dd) * S_ + s] = o;
            }
        }
    }
}

// ---------------------------------------------------------------------------
// Kernel 2: attention. One block per (bh, 128 Q-rows). 4 waves x 32 rows.
// Per 128-t tile: stage K[128][64], Vt[64][128] (swizzled LDS); QK^T MFMA;
// fused *0.125 + mask, exp, write scores+probs to global; P->per-wave LDS;
// PV MFMA accumulate; final context write.
// ---------------------------------------------------------------------------
__global__ __launch_bounds__(256) void attn(
    const u16* __restrict__ Qb, const u16* __restrict__ Kb, const u16* __restrict__ Vt,
    const float* __restrict__ mask,
    float* __restrict__ ctx, float* __restrict__ scores, float* __restrict__ probs)
{
    __shared__ u16 Ks[128 * 64];     // [t][d]
    __shared__ u16 Vs[64 * 128];     // [d][t]
    __shared__ u16 Ps[4][32 * 128];  // per-wave [s_local][t_local]

    const int tid  = threadIdx.x;
    const int lane = tid & 63;
    const int w    = tid >> 6;
    const int l15  = lane & 15;
    const int lg   = lane >> 4;
    const int bh   = blockIdx.y;
    const int mBase = blockIdx.x * 128;
    const int rowQ  = mBase + w * 32;

    // preload Q fragments (A-operand): lane l: row=l&15, k=(l>>4)*8+j
    s16x8 qf[2][2];
    #pragma unroll
    for (int mi = 0; mi < 2; ++mi)
        #pragma unroll
        for (int kk = 0; kk < 2; ++kk)
            qf[mi][kk] = *(const s16x8*)(Qb + ((size_t)bh * S_ + rowQ + mi * 16 + l15) * 64
                                             + kk * 32 + lg * 8);

    f32x4 cacc[2][4] = {};

    for (int tt = 0; tt < S_; tt += 128) {
        __syncthreads();
        // stage K tile (16KB) and Vt tile (16KB): 1024 chunks of 16B each
        #pragma unroll
        for (int i = 0; i < 4; ++i) {
            int chunk = tid + i * 256;
            int rk = chunk >> 3, ck = chunk & 7;     // K: 128 rows x 8 chunks
            s16x8 kv = *(const s16x8*)(Kb + ((size_t)bh * S_ + tt + rk) * 64 + ck * 8);
            *(s16x8*)((char*)Ks + ((rk * 128 + ck * 16) ^ ((rk & 7) << 4))) = kv;
            int rv = chunk >> 4, cv = chunk & 15;    // V: 64 rows x 16 chunks
            s16x8 vv = *(const s16x8*)(Vt + ((size_t)bh * 64 + rv) * S_ + tt + cv * 8);
            *(s16x8*)((char*)Vs + ((rv * 256 + cv * 16) ^ ((rv & 7) << 4))) = vv;
        }
        __syncthreads();

        // QK^T: sacc[mi][ni] over 128 t-cols
        f32x4 sacc[2][8] = {};
        #pragma unroll
        for (int kk = 0; kk < 2; ++kk) {
            s16x8 bfr[8];
            #pragma unroll
            for (int ni = 0; ni < 8; ++ni) {
                int row = ni * 16 + l15;      // t row of K
                int byte = (row * 128 + ((kk * 64 + lg * 16) ^ ((row & 7) << 4)));
                bfr[ni] = *(const s16x8*)((const char*)Ks + byte);
            }
            #pragma unroll
            for (int mi = 0; mi < 2; ++mi)
                #pragma unroll
                for (int ni = 0; ni < 8; ++ni)
                    sacc[mi][ni] = __builtin_amdgcn_mfma_f32_16x16x32_bf16(
                        qf[mi][kk], bfr[ni], sacc[mi][ni], 0, 0, 0);
        }

        // epilogue: scale + mask, exp, write both outputs, stash P in LDS (bf16)
        #pragma unroll
        for (int mi = 0; mi < 2; ++mi) {
            #pragma unroll
            for (int ni = 0; ni < 8; ++ni) {
                #pragma unroll
                for (int j = 0; j < 4; ++j) {
                    int srow = rowQ + mi * 16 + lg * 4 + j;
                    int tcol = tt + ni * 16 + l15;
                    float sc = sacc[mi][ni][j] * 0.125f + mask[(size_t)srow * S_ + tcol];
                    size_t oidx = (size_t)bh * S_ * S_ + (size_t)srow * S_ + tcol;
                    scores[oidx] = sc;
                    float p = __expf(sc);
                    probs[oidx] = p;
                    int lrow = mi * 16 + lg * 4 + j;
                    int lcol = ni * 16 + l15;
                    *(u16*)((char*)Ps[w] + (lrow * 256 + ((lcol * 2) ^ ((lrow & 7) << 4)))) = f2bf(p);
                }
            }
        }

        // PV: cacc += P[32 x 128] * V[128 x 64]
        #pragma unroll
        for (int kv = 0; kv < 4; ++kv) {
            s16x8 pa[2], vb[4];
            #pragma unroll
            for (int mi = 0; mi < 2; ++mi) {
                int row = mi * 16 + l15;
                int byte = (row * 256 + ((kv * 64 + lg * 16) ^ ((row & 7) << 4)));
                pa[mi] = *(const s16x8*)((const char*)Ps[w] + byte);
            }
            #pragma unroll
            for (int ni = 0; ni < 4; ++ni) {
                int row = ni * 16 + l15;      // d row of Vs
                int byte = (row * 256 + ((kv * 64 + lg * 16) ^ ((row & 7) << 4)));
                vb[ni] = *(const s16x8*)((const char*)Vs + byte);
            }
            #pragma unroll
            for (int mi = 0; mi < 2; ++mi)
                #pragma unroll
                for (int ni = 0; ni < 4; ++ni)
                    cacc[mi][ni] = __builtin_amdgcn_mfma_f32_16x16x32_bf16(
                        pa[mi], vb[ni], cacc[mi][ni], 0, 0, 0);
        }
    }

    // write context: ctx[s][b][h*64+d]
    const int b = bh >> 4, h = bh & 15;
    #pragma unroll
    for (int mi = 0; mi < 2; ++mi)
        #pragma unroll
        for (int ni = 0; ni < 4; ++ni)
            #pragma unroll
            for (int j = 0; j < 4; ++j) {
                int srow = rowQ + mi * 16 + lg * 4 + j;
                int dd = ni * 16 + l15;
                ctx[((size_t)srow * B_ + b) * H_ + h * 64 + dd] = cacc[mi][ni][j];
            }
}

extern "C" void kernel_launch(void* const* d_in, const int* in_sizes, int n_in,
                              void* d_out, int out_size, void* d_ws, size_t ws_size,
                              hipStream_t stream) {
    const float* hidden = (const float*)d_in[0];
    const float* mask   = (const float*)d_in[1];
    const float* W      = (const float*)d_in[2];
    const float* bias   = (const float*)d_in[3];

    u16* Qb = (u16*)d_ws;                 // [32][2048][64] bf16
    u16* Kb = Qb + 4194304;               // [32][2048][64] bf16
    u16* Vt = Kb + 4194304;               // [32][64][2048] bf16

    float* out    = (float*)d_out;
    float* ctx    = out;                       // 4194304
    float* scores = out + 4194304;             // 134217728
    float* probs  = out + 138412032;           // 134217728

    qkv_gemm<<<dim3(24, 32), 256, 0, stream>>>(hidden, W, bias, Qb, Kb, Vt);
    attn<<<dim3(16, 32), 256, 0, stream>>>(Qb, Kb, Vt, mask, ctx, scores, probs);
}

// Round 2
// 585.539 us; speedup vs baseline: 1.8319x; 1.8319x over previous
//
#include <hip/hip_runtime.h>
#include <hip/hip_bf16.h>

#define S_  2048
#define B_  2
#define H_  1024
#define NH_ 16
#define D_  64

typedef short s16x8 __attribute__((ext_vector_type(8)));
typedef float f32x4 __attribute__((ext_vector_type(4)));
typedef unsigned short u16;

__device__ __forceinline__ u16 f2bf(float f) {
    __hip_bfloat16 h = __float2bfloat16(f);
    union { __hip_bfloat16 h; u16 u; } c; c.h = h; return c.u;
}

// ---------------------------------------------------------------------------
// Kernel 1: fused QKV projection.  qkv[m][n] = sum_k hidden[m][k]*W[n][k] + b[n]
// Writes bf16:  Q[bh][s][d], K[bh][s][d], Vt[bh][d][s]   (bh = b*16+h)
// ---------------------------------------------------------------------------
__global__ __launch_bounds__(256) void qkv_gemm(
    const float* __restrict__ A, const float* __restrict__ W,
    const float* __restrict__ bias,
    u16* __restrict__ Qb, u16* __restrict__ Kb, u16* __restrict__ Vt)
{
    __shared__ u16 As[128 * 64];
    __shared__ u16 Bs[128 * 64];

    const int tid  = threadIdx.x;
    const int lane = tid & 63;
    const int w    = tid >> 6;
    const int wm   = (w >> 1) * 64;
    const int wn   = (w & 1) * 64;
    const int l15  = lane & 15;
    const int lg   = lane >> 4;
    const int mBase = blockIdx.y * 128;
    const int nBase = blockIdx.x * 128;

    f32x4 acc[4][4] = {};

    for (int kt = 0; kt < 1024; kt += 64) {
        __syncthreads();
        #pragma unroll
        for (int i = 0; i < 8; ++i) {
            int chunk = tid + i * 256;
            int row = chunk >> 4, c4 = chunk & 15;
            float4 av = *(const float4*)(A + (size_t)(mBase + row) * 1024 + kt + c4 * 4);
            float4 bv = *(const float4*)(W + (size_t)(nBase + row) * 1024 + kt + c4 * 4);
            int byte = (row * 128 + c4 * 8) ^ ((row & 7) << 4);
            ushort4 ap; ap.x = f2bf(av.x); ap.y = f2bf(av.y); ap.z = f2bf(av.z); ap.w = f2bf(av.w);
            ushort4 bp; bp.x = f2bf(bv.x); bp.y = f2bf(bv.y); bp.z = f2bf(bv.z); bp.w = f2bf(bv.w);
            *(ushort4*)((char*)As + byte) = ap;
            *(ushort4*)((char*)Bs + byte) = bp;
        }
        __syncthreads();

        #pragma unroll
        for (int kk = 0; kk < 2; ++kk) {
            s16x8 af[4], bfr[4];
            #pragma unroll
            for (int mi = 0; mi < 4; ++mi) {
                int row = wm + mi * 16 + l15;
                int byte = (row * 128 + ((kk * 64 + lg * 16) ^ ((row & 7) << 4)));
                af[mi] = *(const s16x8*)((const char*)As + byte);
            }
            #pragma unroll
            for (int ni = 0; ni < 4; ++ni) {
                int row = wn + ni * 16 + l15;
                int byte = (row * 128 + ((kk * 64 + lg * 16) ^ ((row & 7) << 4)));
                bfr[ni] = *(const s16x8*)((const char*)Bs + byte);
            }
            #pragma unroll
            for (int mi = 0; mi < 4; ++mi)
                #pragma unroll
                for (int ni = 0; ni < 4; ++ni)
                    acc[mi][ni] = __builtin_amdgcn_mfma_f32_16x16x32_bf16(
                        af[mi], bfr[ni], acc[mi][ni], 0, 0, 0);
        }
    }

    #pragma unroll
    for (int ni = 0; ni < 4; ++ni) {
        int gn = nBase + wn + ni * 16 + l15;
        float bv = bias[gn];
        int h  = gn / 192;
        int r  = gn - h * 192;
        int c  = r >> 6;
        int dd = r & 63;
        #pragma unroll
        for (int mi = 0; mi < 4; ++mi) {
            #pragma unroll
            for (int j = 0; j < 4; ++j) {
                int m = mBase + wm + mi * 16 + lg * 4 + j;
                float val = acc[mi][ni][j] + bv;
                int s = m >> 1, b = m & 1;
                int bh = b * 16 + h;
                u16 o = f2bf(val);
                if (c == 0)      Qb[((size_t)bh * S_ + s) * 64 + dd] = o;
                else if (c == 1) Kb[((size_t)bh * S_ + s) * 64 + dd] = o;
                else             Vt[((size_t)bh * 64 + dd) * S_ + s] = o;
            }
        }
    }
}

// ---------------------------------------------------------------------------
// Kernel 2: attention. Block = (bh, 64 Q-rows), 4 waves x 16 rows.
// Swapped QK^T: D[t][q] so each lane owns 4 consecutive t -> float4 I/O on
// mask/scores/probs. P->PV round-trips through a tiny per-wave LDS chunk
// (32 t-cols at a time), interleaved with PV MFMAs.
// ---------------------------------------------------------------------------
__global__ __launch_bounds__(256, 4) void attn(
    const u16* __restrict__ Qb, const u16* __restrict__ Kb, const u16* __restrict__ Vt,
    const float* __restrict__ mask,
    float* __restrict__ ctx, float* __restrict__ scores, float* __restrict__ probs)
{
    __shared__ u16 Ks[128 * 64];       // [t][d] swizzled, 16 KB
    __shared__ u16 Vs[64 * 128];       // [d][t] swizzled, 16 KB
    __shared__ u16 Ps[4][16 * 40];     // per-wave [q][40] (pad to 80B stride), 5 KB

    const int tid  = threadIdx.x;
    const int lane = tid & 63;
    const int w    = tid >> 6;
    const int l15  = lane & 15;
    const int lg   = lane >> 4;
    const int bh   = blockIdx.y;
    const int rowQ = blockIdx.x * 64 + w * 16;

    // Q fragments (B-operand): lane l: col q = l&15, k = (l>>4)*8+j
    s16x8 qf[2];
    #pragma unroll
    for (int kk = 0; kk < 2; ++kk)
        qf[kk] = *(const s16x8*)(Qb + ((size_t)bh * S_ + rowQ + l15) * 64 + kk * 32 + lg * 8);

    f32x4 cacc[4] = {};   // D[q][d]: 16 q-rows x 64 d

    for (int tt = 0; tt < S_; tt += 128) {
        __syncthreads();
        // stage K[128][64] and Vt[64][128] tiles (16 KB each)
        #pragma unroll
        for (int i = 0; i < 4; ++i) {
            int chunk = tid + i * 256;
            int rk = chunk >> 3, ck = chunk & 7;
            s16x8 kv = *(const s16x8*)(Kb + ((size_t)bh * S_ + tt + rk) * 64 + ck * 8);
            *(s16x8*)((char*)Ks + ((rk * 128 + ck * 16) ^ ((rk & 7) << 4))) = kv;
            int rv = chunk >> 4, cv = chunk & 15;
            s16x8 vv = *(const s16x8*)(Vt + ((size_t)bh * 64 + rv) * S_ + tt + cv * 8);
            *(s16x8*)((char*)Vs + ((rv * 256 + cv * 16) ^ ((rv & 7) << 4))) = vv;
        }
        __syncthreads();

        // QK^T swapped: sacc[tb] = D[t=tb*16+lg*4+j][q=l15]
        f32x4 sacc[8] = {};
        #pragma unroll
        for (int kk = 0; kk < 2; ++kk) {
            #pragma unroll
            for (int tb = 0; tb < 8; ++tb) {
                int row = tb * 16 + l15;
                int byte = (row * 128 + ((kk * 64 + lg * 16) ^ ((row & 7) << 4)));
                s16x8 kf = *(const s16x8*)((const char*)Ks + byte);
                sacc[tb] = __builtin_amdgcn_mfma_f32_16x16x32_bf16(
                    kf, qf[kk], sacc[tb], 0, 0, 0);
            }
        }

        // epilogue + PV, 32 t-cols at a time
        const int q = rowQ + l15;
        #pragma unroll
        for (int kv = 0; kv < 4; ++kv) {
            #pragma unroll
            for (int th = 0; th < 2; ++th) {
                int tb = kv * 2 + th;
                int tbase = tt + tb * 16 + lg * 4;
                size_t base = (size_t)bh * S_ * S_ + (size_t)q * S_ + tbase;
                float4 mv = *(const float4*)(mask + (size_t)q * S_ + tbase);
                f32x4 sc = sacc[tb];
                float4 s4;
                s4.x = sc[0] * 0.125f + mv.x;
                s4.y = sc[1] * 0.125f + mv.y;
                s4.z = sc[2] * 0.125f + mv.z;
                s4.w = sc[3] * 0.125f + mv.w;
                *(float4*)(scores + base) = s4;
                float4 p4;
                p4.x = __expf(s4.x); p4.y = __expf(s4.y);
                p4.z = __expf(s4.z); p4.w = __expf(s4.w);
                *(float4*)(probs + base) = p4;
                ushort4 pb;
                pb.x = f2bf(p4.x); pb.y = f2bf(p4.y);
                pb.z = f2bf(p4.z); pb.w = f2bf(p4.w);
                *(ushort4*)((char*)Ps[w] + l15 * 80 + th * 32 + lg * 8) = pb;
            }
            // PV for this 32-col chunk: cacc[db] += P[q][t'] * V[t'][d]
            s16x8 pa = *(const s16x8*)((const char*)Ps[w] + l15 * 80 + lg * 16);
            #pragma unroll
            for (int db = 0; db < 4; ++db) {
                int row = db * 16 + l15;
                int byte = (row * 256 + ((kv * 64 + lg * 16) ^ ((row & 7) << 4)));
                s16x8 vb = *(const s16x8*)((const char*)Vs + byte);
                cacc[db] = __builtin_amdgcn_mfma_f32_16x16x32_bf16(
                    pa, vb, cacc[db], 0, 0, 0);
            }
        }
    }

    // write context: ctx[s][b][h*64+d]
    const int b = bh >> 4, h = bh & 15;
    #pragma unroll
    for (int db = 0; db < 4; ++db)
        #pragma unroll
        for (int j = 0; j < 4; ++j) {
            int srow = rowQ + lg * 4 + j;
            int dd = db * 16 + l15;
            ctx[((size_t)srow * B_ + b) * H_ + h * 64 + dd] = cacc[db][j];
        }
}

extern "C" void kernel_launch(void* const* d_in, const int* in_sizes, int n_in,
                              void* d_out, int out_size, void* d_ws, size_t ws_size,
                              hipStream_t stream) {
    const float* hidden = (const float*)d_in[0];
    const float* mask   = (const float*)d_in[1];
    const float* W      = (const float*)d_in[2];
    const float* bias   = (const float*)d_in[3];

    u16* Qb = (u16*)d_ws;
    u16* Kb = Qb + 4194304;
    u16* Vt = Kb + 4194304;

    float* out    = (float*)d_out;
    float* ctx    = out;
    float* scores = out + 4194304;
    float* probs  = out + 138412032;

    qkv_gemm<<<dim3(24, 32), 256, 0, stream>>>(hidden, W, bias, Qb, Kb, Vt);
    attn<<<dim3(32, 32), 256, 0, stream>>>(Qb, Kb, Vt, mask, ctx, scores, probs);
}

// Round 4
// 395.609 us; speedup vs baseline: 2.7114x; 1.4801x over previous
//
#include <hip/hip_runtime.h>
#include <hip/hip_bf16.h>

#define S_  2048
#define B_  2
#define H_  1024
#define NH_ 16
#define D_  64

typedef short s16x8 __attribute__((ext_vector_type(8)));
typedef float f32x4 __attribute__((ext_vector_type(4)));
typedef unsigned short u16;

__device__ __forceinline__ u16 f2bf(float f) {
    __hip_bfloat16 h = __float2bfloat16(f);
    union { __hip_bfloat16 h; u16 u; } c; c.h = h; return c.u;
}

#define GLOAD_LDS16(g, l) __builtin_amdgcn_global_load_lds( \
    (const __attribute__((address_space(1))) void*)(g),     \
    (__attribute__((address_space(3))) void*)(l), 16, 0, 0)

// ---------------------------------------------------------------------------
// Kernel 1: fused QKV projection (unchanged from R2).
// Writes bf16:  Q[bh][s][d], K[bh][s][d], Vt[bh][d][s]   (bh = b*16+h)
// ---------------------------------------------------------------------------
__global__ __launch_bounds__(256) void qkv_gemm(
    const float* __restrict__ A, const float* __restrict__ W,
    const float* __restrict__ bias,
    u16* __restrict__ Qb, u16* __restrict__ Kb, u16* __restrict__ Vt)
{
    __shared__ u16 As[128 * 64];
    __shared__ u16 Bs[128 * 64];

    const int tid  = threadIdx.x;
    const int lane = tid & 63;
    const int w    = tid >> 6;
    const int wm   = (w >> 1) * 64;
    const int wn   = (w & 1) * 64;
    const int l15  = lane & 15;
    const int lg   = lane >> 4;
    const int mBase = blockIdx.y * 128;
    const int nBase = blockIdx.x * 128;

    f32x4 acc[4][4] = {};

    for (int kt = 0; kt < 1024; kt += 64) {
        __syncthreads();
        #pragma unroll
        for (int i = 0; i < 8; ++i) {
            int chunk = tid + i * 256;
            int row = chunk >> 4, c4 = chunk & 15;
            float4 av = *(const float4*)(A + (size_t)(mBase + row) * 1024 + kt + c4 * 4);
            float4 bv = *(const float4*)(W + (size_t)(nBase + row) * 1024 + kt + c4 * 4);
            int byte = (row * 128 + c4 * 8) ^ ((row & 7) << 4);
            ushort4 ap; ap.x = f2bf(av.x); ap.y = f2bf(av.y); ap.z = f2bf(av.z); ap.w = f2bf(av.w);
            ushort4 bp; bp.x = f2bf(bv.x); bp.y = f2bf(bv.y); bp.z = f2bf(bv.z); bp.w = f2bf(bv.w);
            *(ushort4*)((char*)As + byte) = ap;
            *(ushort4*)((char*)Bs + byte) = bp;
        }
        __syncthreads();

        #pragma unroll
        for (int kk = 0; kk < 2; ++kk) {
            s16x8 af[4], bfr[4];
            #pragma unroll
            for (int mi = 0; mi < 4; ++mi) {
                int row = wm + mi * 16 + l15;
                int byte = (row * 128 + ((kk * 64 + lg * 16) ^ ((row & 7) << 4)));
                af[mi] = *(const s16x8*)((const char*)As + byte);
            }
            #pragma unroll
            for (int ni = 0; ni < 4; ++ni) {
                int row = wn + ni * 16 + l15;
                int byte = (row * 128 + ((kk * 64 + lg * 16) ^ ((row & 7) << 4)));
                bfr[ni] = *(const s16x8*)((const char*)Bs + byte);
            }
            #pragma unroll
            for (int mi = 0; mi < 4; ++mi)
                #pragma unroll
                for (int ni = 0; ni < 4; ++ni)
                    acc[mi][ni] = __builtin_amdgcn_mfma_f32_16x16x32_bf16(
                        af[mi], bfr[ni], acc[mi][ni], 0, 0, 0);
        }
    }

    #pragma unroll
    for (int ni = 0; ni < 4; ++ni) {
        int gn = nBase + wn + ni * 16 + l15;
        float bv = bias[gn];
        int h  = gn / 192;
        int r  = gn - h * 192;
        int c  = r >> 6;
        int dd = r & 63;
        #pragma unroll
        for (int mi = 0; mi < 4; ++mi) {
            #pragma unroll
            for (int j = 0; j < 4; ++j) {
                int m = mBase + wm + mi * 16 + lg * 4 + j;
                float val = acc[mi][ni][j] + bv;
                int s = m >> 1, b = m & 1;
                int bh = b * 16 + h;
                u16 o = f2bf(val);
                if (c == 0)      Qb[((size_t)bh * S_ + s) * 64 + dd] = o;
                else if (c == 1) Kb[((size_t)bh * S_ + s) * 64 + dd] = o;
                else             Vt[((size_t)bh * 64 + dd) * S_ + s] = o;
            }
        }
    }
}

// ---------------------------------------------------------------------------
// Kernel 2: attention. Block = (bh, 64 Q-rows), 4 waves x 16 rows.
// 64-t tiles, double-buffered K/V staged by global_load_lds (pre-swizzled
// source, linear LDS dest, XOR-swizzled reads). ONE barrier per tile:
// stage(t+1) flies across compute(t). Nontemporal streaming stores.
// ---------------------------------------------------------------------------
__global__ __launch_bounds__(256, 4) void attn(
    const u16* __restrict__ Qb, const u16* __restrict__ Kb, const u16* __restrict__ Vt,
    const float* __restrict__ mask,
    float* __restrict__ ctx, float* __restrict__ scores, float* __restrict__ probs)
{
    __shared__ u16 Ks[2][64 * 64];     // [t][d] swizzled, 8 KB each
    __shared__ u16 Vs[2][64 * 64];     // [d][t] swizzled, 8 KB each
    __shared__ u16 Ps[4][16 * 40];     // per-wave [q][40] (80B stride), 5 KB

    const int tid  = threadIdx.x;
    const int lane = tid & 63;
    const int w    = tid >> 6;
    const int l15  = lane & 15;
    const int lg   = lane >> 4;

    // XCD-chunked swizzle: XCD k owns orig-blocks [k*128, k*128+128) = 4 bh
    const int lin  = blockIdx.y * 32 + blockIdx.x;
    const int orig = (lin & 7) * 128 + (lin >> 3);
    const int bh   = orig >> 5;
    const int rowQ = (orig & 31) * 64 + w * 16;

    // staging addresses (pre-swizzled source chunks), wave-uniform LDS bases
    const int nK = (w * 2) * 64 + lane;          // first of 2 K chunk-ids
    const int rK0 = nK >> 3, cK0 = (nK & 7) ^ (rK0 & 7);
    const int nK1 = nK + 64;
    const int rK1 = nK1 >> 3, cK1 = (nK1 & 7) ^ (rK1 & 7);

    // Q fragments (B-operand): lane l: col q = l&15, k = lg*8+j
    s16x8 qf[2];
    #pragma unroll
    for (int kk = 0; kk < 2; ++kk)
        qf[kk] = *(const s16x8*)(Qb + ((size_t)bh * S_ + rowQ + l15) * 64 + kk * 32 + lg * 8);

    f32x4 cacc[4] = {};   // D[q][d]: 16 q-rows x 64 d

    // stage tile tt into buffer buf
    auto stage = [&](int buf, int tt) {
        const u16* kbase = Kb + (size_t)bh * S_ * 64 + (size_t)tt * 64;
        const u16* vbase = Vt + (size_t)bh * 64 * S_ + tt;
        GLOAD_LDS16(kbase + (size_t)rK0 * 64 + cK0 * 8, &Ks[buf][(w * 2 + 0) * 512]);
        GLOAD_LDS16(kbase + (size_t)rK1 * 64 + cK1 * 8, &Ks[buf][(w * 2 + 1) * 512]);
        GLOAD_LDS16(vbase + (size_t)rK0 * S_ + cK0 * 8, &Vs[buf][(w * 2 + 0) * 512]);
        GLOAD_LDS16(vbase + (size_t)rK1 * S_ + cK1 * 8, &Vs[buf][(w * 2 + 1) * 512]);
    };

    stage(0, 0);
    int cur = 0;

    for (int tt = 0; tt < S_; tt += 64) {
        __syncthreads();                    // stage(cur) done + all readers past buf(cur^1)
        if (tt + 64 < S_) stage(cur ^ 1, tt + 64);

        // QK^T swapped: sacc[tb] = D[t = tb*16+lg*4+j][q = l15]
        f32x4 sacc[4] = {};
        #pragma unroll
        for (int kk = 0; kk < 2; ++kk) {
            #pragma unroll
            for (int tb = 0; tb < 4; ++tb) {
                int row = tb * 16 + l15;
                int byte = (row * 128 + ((kk * 64 + lg * 16) ^ ((row & 7) << 4)));
                s16x8 kf = *(const s16x8*)((const char*)Ks[cur] + byte);
                sacc[tb] = __builtin_amdgcn_mfma_f32_16x16x32_bf16(
                    kf, qf[kk], sacc[tb], 0, 0, 0);
            }
        }

        // epilogue + PV, 32 t-cols at a time
        const int q = rowQ + l15;
        #pragma unroll
        for (int kv = 0; kv < 2; ++kv) {
            #pragma unroll
            for (int th = 0; th < 2; ++th) {
                int tb = kv * 2 + th;
                int tbase = tt + tb * 16 + lg * 4;
                size_t base = (size_t)bh * S_ * S_ + (size_t)q * S_ + tbase;
                f32x4 mv = *(const f32x4*)(mask + (size_t)q * S_ + tbase);
                f32x4 sc = sacc[tb];
                f32x4 s4;
                s4[0] = sc[0] * 0.125f + mv[0];
                s4[1] = sc[1] * 0.125f + mv[1];
                s4[2] = sc[2] * 0.125f + mv[2];
                s4[3] = sc[3] * 0.125f + mv[3];
                __builtin_nontemporal_store(s4, (f32x4*)(scores + base));
                f32x4 p4;
                p4[0] = __expf(s4[0]); p4[1] = __expf(s4[1]);
                p4[2] = __expf(s4[2]); p4[3] = __expf(s4[3]);
                __builtin_nontemporal_store(p4, (f32x4*)(probs + base));
                ushort4 pb;
                pb.x = f2bf(p4[0]); pb.y = f2bf(p4[1]);
                pb.z = f2bf(p4[2]); pb.w = f2bf(p4[3]);
                *(ushort4*)((char*)Ps[w] + l15 * 80 + th * 32 + lg * 8) = pb;
            }
            // PV for this 32-col chunk: cacc[db] += P[q][t'] * V[t'][d]
            s16x8 pa = *(const s16x8*)((const char*)Ps[w] + l15 * 80 + lg * 16);
            #pragma unroll
            for (int db = 0; db < 4; ++db) {
                int row = db * 16 + l15;
                int byte = (row * 128 + ((kv * 64 + lg * 16) ^ ((row & 7) << 4)));
                s16x8 vb = *(const s16x8*)((const char*)Vs[cur] + byte);
                cacc[db] = __builtin_amdgcn_mfma_f32_16x16x32_bf16(
                    pa, vb, cacc[db], 0, 0, 0);
            }
        }
        cur ^= 1;
    }

    // write context: ctx[s][b][h*64+d]
    const int b = bh >> 4, h = bh & 15;
    #pragma unroll
    for (int db = 0; db < 4; ++db)
        #pragma unroll
        for (int j = 0; j < 4; ++j) {
            int srow = rowQ + lg * 4 + j;
            int dd = db * 16 + l15;
            __builtin_nontemporal_store(cacc[db][j],
                ctx + ((size_t)srow * B_ + b) * H_ + h * 64 + dd);
        }
}

extern "C" void kernel_launch(void* const* d_in, const int* in_sizes, int n_in,
                              void* d_out, int out_size, void* d_ws, size_t ws_size,
                              hipStream_t stream) {
    const float* hidden = (const float*)d_in[0];
    const float* mask   = (const float*)d_in[1];
    const float* W      = (const float*)d_in[2];
    const float* bias   = (const float*)d_in[3];

    u16* Qb = (u16*)d_ws;
    u16* Kb = Qb + 4194304;
    u16* Vt = Kb + 4194304;

    float* out    = (float*)d_out;
    float* ctx    = out;
    float* scores = out + 4194304;
    float* probs  = out + 138412032;

    qkv_gemm<<<dim3(24, 32), 256, 0, stream>>>(hidden, W, bias, Qb, Kb, Vt);
    attn<<<dim3(32, 32), 256, 0, stream>>>(Qb, Kb, Vt, mask, ctx, scores, probs);
}